// Round 6
// baseline (179.510 us; speedup 1.0000x reference)
//
#include <hip/hip_runtime.h>
#include <stdint.h>

#define L_SEQ 2048
#define BATCH 2
#define DMODEL 512
#define PROJ 1024
#define NST 32
#define NCAT 1152   // 1024 (Wd) + 32 (WB) + 32 (WC) + 64 pad -> multiple of 128
#define ROWS (BATCH*L_SEQ)  // 4096
#define THRESH 50.0f        // suffix cutoff (nats)

typedef float f32x4 __attribute__((ext_vector_type(4)));
typedef short short8 __attribute__((ext_vector_type(8)));

__device__ inline float bf2f(unsigned short u){ uint32_t x=((uint32_t)u)<<16; float f; __builtin_memcpy(&f,&x,4); return f; }
__device__ inline unsigned short f2bf(float f){ uint32_t x; __builtin_memcpy(&x,&f,4); uint32_t r=x+0x7FFFu+((x>>16)&1u); return (unsigned short)(r>>16); }
__device__ inline float siluf(float x){ return x/(1.f+__expf(-x)); }
__device__ inline float softplusf(float x){ return x>20.f? x : log1pf(__expf(x)); }

#define AS1(p) ((const __attribute__((address_space(1))) void*)(p))
#define AS3(p) ((__attribute__((address_space(3))) void*)(p))

template<int N> __device__ inline void wait_vmcnt(){
  if constexpr (N==0)      asm volatile("s_waitcnt vmcnt(0)" ::: "memory");
  else if constexpr (N==1) asm volatile("s_waitcnt vmcnt(1)" ::: "memory");
  else if constexpr (N==2) asm volatile("s_waitcnt vmcnt(2)" ::: "memory");
  else if constexpr (N==3) asm volatile("s_waitcnt vmcnt(3)" ::: "memory");
  else if constexpr (N==4) asm volatile("s_waitcnt vmcnt(4)" ::: "memory");
  else if constexpr (N==5) asm volatile("s_waitcnt vmcnt(5)" ::: "memory");
  else if constexpr (N==6) asm volatile("s_waitcnt vmcnt(6)" ::: "memory");
  else                     asm volatile("s_waitcnt vmcnt(8)" ::: "memory");
}

// ---------------- weight prep: fp32 -> bf16 transposed / concatenated ----------------
__global__ __launch_bounds__(256)
void prep_kernel(const float* __restrict__ W1, const float* __restrict__ b1,
                 const float* __restrict__ W2, const float* __restrict__ b2,
                 const float* __restrict__ Wd, const float* __restrict__ bd,
                 const float* __restrict__ WB, const float* __restrict__ bB,
                 const float* __restrict__ WC, const float* __restrict__ bC,
                 const float* __restrict__ W3,
                 unsigned short* __restrict__ W12t, unsigned short* __restrict__ Wcatt,
                 unsigned short* __restrict__ W3t, float* __restrict__ bias12,
                 float* __restrict__ biascat)
{
  int i = blockIdx.x*256 + threadIdx.x;
  const int nA = 2048*512;        // W12t [2048][512]
  const int nB = NCAT*1024;       // Wcatt [1152][1024]
  const int nC = 512*1024;        // W3t  [512][1024]
  if (i < nA) {
    int n = i >> 9, k = i & 511;
    float v = (n < 1024) ? W1[k*1024 + n] : W2[k*1024 + (n-1024)];
    W12t[i] = f2bf(v);
    return;
  }
  i -= nA;
  if (i < nB) {
    int n = i >> 10, k = i & 1023;
    float v;
    if (n < 1024) v = Wd[k*1024 + n];
    else if (n < 1056) v = WB[k*32 + (n-1024)];
    else if (n < 1088) v = WC[k*32 + (n-1056)];
    else v = 0.f;
    Wcatt[i] = f2bf(v);
    return;
  }
  i -= nB;
  if (i < nC) {
    int n = i >> 10, k = i & 1023;
    W3t[i] = f2bf(W3[k*512 + n]);
    return;
  }
  i -= nC;
  if (i < 2048) { bias12[i] = (i < 1024) ? b1[i] : b2[i-1024]; return; }
  i -= 2048;
  if (i < NCAT) {
    biascat[i] = (i < 1024) ? bd[i] : (i < 1056) ? bB[i-1024] : (i < 1088) ? bC[i-1056] : 0.f;
  }
}

// ---------------- LayerNorm: one wave per row of 512, write bf16 ----------------
__global__ __launch_bounds__(256)
void ln_kernel(const float* __restrict__ x, const float* __restrict__ gamma,
               const float* __restrict__ beta, unsigned short* __restrict__ H)
{
  int row = blockIdx.x*4 + (threadIdx.x >> 6);
  int lane = threadIdx.x & 63;
  const float4* xr = (const float4*)(x + (size_t)row*DMODEL);
  float4 v0 = xr[lane];
  float4 v1 = xr[lane+64];
  float s = v0.x+v0.y+v0.z+v0.w + v1.x+v1.y+v1.z+v1.w;
  float q = v0.x*v0.x+v0.y*v0.y+v0.z*v0.z+v0.w*v0.w
          + v1.x*v1.x+v1.y*v1.y+v1.z*v1.z+v1.w*v1.w;
#pragma unroll
  for (int m=32;m>0;m>>=1){ s += __shfl_xor(s,m); q += __shfl_xor(q,m); }
  float mu = s*(1.f/DMODEL);
  float var = q*(1.f/DMODEL) - mu*mu;
  float rs = rsqrtf(var + 1e-3f);
  int c0 = lane*4, c1 = 256 + lane*4;
  float4 g0 = *(const float4*)&gamma[c0]; float4 g1 = *(const float4*)&gamma[c1];
  float4 t0 = *(const float4*)&beta[c0];  float4 t1 = *(const float4*)&beta[c1];
  ushort4 o0, o1;
  o0.x = f2bf((v0.x-mu)*rs*g0.x + t0.x);
  o0.y = f2bf((v0.y-mu)*rs*g0.y + t0.y);
  o0.z = f2bf((v0.z-mu)*rs*g0.z + t0.z);
  o0.w = f2bf((v0.w-mu)*rs*g0.w + t0.w);
  o1.x = f2bf((v1.x-mu)*rs*g1.x + t1.x);
  o1.y = f2bf((v1.y-mu)*rs*g1.y + t1.y);
  o1.z = f2bf((v1.z-mu)*rs*g1.z + t1.z);
  o1.w = f2bf((v1.w-mu)*rs*g1.w + t1.w);
  *(ushort4*)&H[(size_t)row*DMODEL + c0] = o0;
  *(ushort4*)&H[(size_t)row*DMODEL + c1] = o1;
}

// ---------------- bf16 GEMM: waves split M, each wave owns (BM/WAVES) x BN ----------------
// Raises register reuse: per wave-iter LDS read = (AM+AN) KB for AM*AN MFMAs.
// Depth-2 prefetch, triple-buffer LDS, counted vmcnt. BK=32.
// MODE 0: +bias -> bf16. MODE 2: +bias, softplus col<1024 -> fp32. MODE 3: +bias+res -> fp32.
template<int BM, int BN, int WAVES, int MODE>
__global__ __launch_bounds__(WAVES*64)
void gemm_bt(const unsigned short* __restrict__ A, const unsigned short* __restrict__ Bt,
             void* __restrict__ Cv, const float* __restrict__ bias,
             const float* __restrict__ res, int M, int N, int K)
{
  constexpr int THREADS = WAVES*64;
  constexpr int BMW = BM/WAVES;
  constexpr int AM = BMW/16, AN = BN/16;
  constexpr int ASEGI = BM*4/THREADS;   // gload_lds insts per wave for A per K-step
  constexpr int BSEGI = BN*4/THREADS;
  constexpr int LPT = ASEGI + BSEGI;
  __shared__ unsigned short As[3][BM*32];
  __shared__ unsigned short Bs[3][BN*32];
  int tid = threadIdx.x;
  int lane = tid & 63, wid = tid >> 6;
  int m0 = blockIdx.x*BM, n0 = blockIdx.y*BN;

  f32x4 acc[AM][AN];
#pragma unroll
  for (int i=0;i<AM;i++)
#pragma unroll
    for (int j=0;j<AN;j++)
#pragma unroll
      for (int e=0;e<4;e++) acc[i][j][e] = 0.f;

  // per-thread source pointers (hoisted; advance 32 elems per stage)
  // LDS seg s = (row=s>>2, slot=s&3); slot holds k-chunk slot^(row&3)  [XOR swizzle on source]
  const unsigned short* ap[ASEGI];
  const unsigned short* bp[BSEGI];
#pragma unroll
  for (int j=0;j<ASEGI;j++){
    int s = tid + j*THREADS;
    int row = s >> 2, kc = ((s & 3) ^ (row & 3)) * 8;
    ap[j] = A + (size_t)(m0+row)*K + kc;
  }
#pragma unroll
  for (int j=0;j<BSEGI;j++){
    int s = tid + j*THREADS;
    int row = s >> 2, kc = ((s & 3) ^ (row & 3)) * 8;
    bp[j] = Bt + (size_t)(n0+row)*K + kc;
  }

  auto stage = [&](int buf){
#pragma unroll
    for (int j=0;j<ASEGI;j++){
      __builtin_amdgcn_global_load_lds(AS1(ap[j]), AS3(&As[buf][(size_t)(j*THREADS + wid*64)*8]), 16, 0, 0);
      ap[j] += 32;
    }
#pragma unroll
    for (int j=0;j<BSEGI;j++){
      __builtin_amdgcn_global_load_lds(AS1(bp[j]), AS3(&Bs[buf][(size_t)(j*THREADS + wid*64)*8]), 16, 0, 0);
      bp[j] += 32;
    }
  };

  stage(0);
  stage(1);
  int T = K/32;
  int rb = 0, wb = 2;
  int r = lane & 15, kb = lane >> 4;
  int kbx = kb ^ (r & 3);                  // swizzled k-chunk slot for this lane's rows
  for (int t = 0; t < T; ++t) {
    if (t+1 < T) wait_vmcnt<LPT>();        // stage(t) complete; stage(t+1) stays in flight
    else         wait_vmcnt<0>();
    __builtin_amdgcn_s_barrier();          // buf rb fully populated; reads of wb done
    if (t+2 < T) { stage(wb); wb = (wb==2)?0:wb+1; }
    short8 af[AM], bfr[AN];
#pragma unroll
    for (int i=0;i<AM;i++) af[i]  = *(const short8*)&As[rb][((wid*BMW + i*16 + r)*4 + kbx)*8];
#pragma unroll
    for (int j=0;j<AN;j++) bfr[j] = *(const short8*)&Bs[rb][((j*16 + r)*4 + kbx)*8];
#pragma unroll
    for (int i=0;i<AM;i++)
#pragma unroll
      for (int j=0;j<AN;j++)
        acc[i][j] = __builtin_amdgcn_mfma_f32_16x16x32_bf16(af[i], bfr[j], acc[i][j], 0,0,0);
    rb = (rb==2)?0:rb+1;
  }

  int rr = (lane >> 4)*4, cc = lane & 15;
#pragma unroll
  for (int i=0;i<AM;i++)
#pragma unroll
    for (int j=0;j<AN;j++) {
      int col = n0 + j*16 + cc;
      float bv = bias[col];
#pragma unroll
      for (int e=0;e<4;e++) {
        int row = m0 + wid*BMW + i*16 + rr + e;
        float v = acc[i][j][e] + bv;
        if (MODE == 0) {
          ((unsigned short*)Cv)[(size_t)row*N + col] = f2bf(v);
        } else if (MODE == 2) {
          if (col < 1024) v = softplusf(v);
          ((float*)Cv)[(size_t)row*N + col] = v;
        } else {
          v += res[(size_t)row*N + col];
          ((float*)Cv)[(size_t)row*N + col] = v;
        }
      }
    }
}

// ---------------- causal depthwise conv (K=4) + SiLU; also SiLU for x2 (bf16 in) ----------------
__global__ __launch_bounds__(256)
void conv_silu_kernel(const unsigned short* __restrict__ P12, const float* __restrict__ ck,
                      const float* __restrict__ cb, unsigned short* __restrict__ ubf,
                      unsigned short* __restrict__ x2bf)
{
  int gid = blockIdx.x*256 + threadIdx.x;   // ROWS * 512 tasks
  int c4 = gid & 511;
  int row = gid >> 9;
  int l = row & (L_SEQ-1);
  if (c4 < 256) {
    int c = c4*4;
    float4 bv = *(const float4*)&cb[c];
    float r0=bv.x, r1=bv.y, r2=bv.z, r3=bv.w;
#pragma unroll
    for (int t=0;t<4;t++){
      int lsrc = l - 3 + t;
      if (lsrc >= 0) {
        ushort4 xv = *(const ushort4*)&P12[(size_t)(row-3+t)*2048 + c];
        float4 kv = *(const float4*)&ck[t*PROJ + c];
        r0 = fmaf(bf2f(xv.x),kv.x,r0);
        r1 = fmaf(bf2f(xv.y),kv.y,r1);
        r2 = fmaf(bf2f(xv.z),kv.z,r2);
        r3 = fmaf(bf2f(xv.w),kv.w,r3);
      }
    }
    ushort4 o;
    o.x=f2bf(siluf(r0)); o.y=f2bf(siluf(r1)); o.z=f2bf(siluf(r2)); o.w=f2bf(siluf(r3));
    *(ushort4*)&ubf[(size_t)row*PROJ + c] = o;
  } else {
    int c = (c4-256)*4;
    ushort4 xv = *(const ushort4*)&P12[(size_t)row*2048 + 1024 + c];
    ushort4 o;
    o.x=f2bf(siluf(bf2f(xv.x))); o.y=f2bf(siluf(bf2f(xv.y)));
    o.z=f2bf(siluf(bf2f(xv.z))); o.w=f2bf(siluf(bf2f(xv.w)));
    *(ushort4*)&x2bf[(size_t)row*PROJ + c] = o;
  }
}

// ---------------- delta transpose: P3[:, :1024] -> deltaT[b*1024+d][l] ----------------
__global__ __launch_bounds__(256)
void dtrans_kernel(const float* __restrict__ P3, float* __restrict__ deltaT)
{
  __shared__ float tile[32][33];
  int bz = blockIdx.z;
  int l0t = blockIdx.x*32, d0t = blockIdx.y*32;
  int lx = threadIdx.x & 31, ly = threadIdx.x >> 5;   // ly 0..7
#pragma unroll
  for (int i=0;i<4;i++)
    tile[ly+i*8][lx] = P3[(size_t)(bz*L_SEQ + l0t + ly + i*8)*NCAT + d0t + lx];
  __syncthreads();
#pragma unroll
  for (int i=0;i<4;i++)
    deltaT[(size_t)(bz*PROJ + d0t + ly + i*8)*L_SEQ + l0t + lx] = tile[lx][ly+i*8];
}

// ---------------- per-(b,d): shifted suffix sums sufsh[l]=sum_{l+1..end}, l0 ----------------
__global__ __launch_bounds__(256)
void tsum_kernel(const float* __restrict__ deltaT, float* __restrict__ sufshT,
                 int* __restrict__ l0out)
{
  int G = blockIdx.x;
  const float* row = deltaT + (size_t)G*L_SEQ;
  int t = threadIdx.x;
  float4 v0 = *(const float4*)&row[t*8];
  float4 v1 = *(const float4*)&row[t*8+4];
  float vals[8] = {v0.x,v0.y,v0.z,v0.w,v1.x,v1.y,v1.z,v1.w};
  float part = 0.f;
#pragma unroll
  for (int i=0;i<8;i++) part += vals[i];
  __shared__ float ps[256];
  ps[t] = part; __syncthreads();
  for (int off=1; off<256; off<<=1){
    float v = (t >= off) ? ps[t-off] : 0.f;
    __syncthreads();
    ps[t] += v;
    __syncthreads();
  }
  float T = ps[255];
  float prefx = ps[t] - part;      // exclusive prefix of this thread's chunk
  float run = prefx; int cnt = 0; float out[8];
#pragma unroll
  for (int i=0;i<8;i++){
    float suf_l = T - run;                  // suffix starting at l (inclusive)
    cnt += (suf_l >= THRESH) ? 1 : 0;
    run += vals[i];
    out[i] = T - run;                        // suffix starting at l+1
  }
  *(float4*)&sufshT[(size_t)G*L_SEQ + t*8]     = make_float4(out[0],out[1],out[2],out[3]);
  *(float4*)&sufshT[(size_t)G*L_SEQ + t*8 + 4] = make_float4(out[4],out[5],out[6],out[7]);
  __shared__ int cs[256];
  cs[t] = cnt; __syncthreads();
  for (int off=128; off>0; off>>=1){ if (t < off) cs[t] += cs[t+off]; __syncthreads(); }
  if (t == 0) {
    int total = cs[0];
    l0out[G] = total > 0 ? total-1 : 0;   // last l with suf[l] >= THRESH
  }
}

// ---------------- windowed gated selective scan, batch-8 pipelined ----------------
__global__ __launch_bounds__(256)
void scan_kernel(const float* __restrict__ deltaT, const float* __restrict__ sufshT,
                 const float* __restrict__ P3, const unsigned short* __restrict__ ubf,
                 const float* __restrict__ A_log, const int* __restrict__ l0arr,
                 float* __restrict__ ystate)
{
  int tid = threadIdx.x;
  int n = tid & 31;
  int G = blockIdx.x*8 + (tid >> 5);
  int b = G >> 10, d = G & 1023;
  float np1 = __expf(A_log[d*NST + n]);   // -A[d,n] = n+1
  int myl0 = l0arr[G];
  int base = min(myl0, __shfl_xor(myl0, 32)) & ~7;   // wave-uniform, 8-aligned
  const float* dT = deltaT + (size_t)G*L_SEQ;
  const float* sT = sufshT + (size_t)G*L_SEQ;
  const float* P3b = P3 + (size_t)b*L_SEQ*NCAT + 1024 + n;
  const unsigned short* ub = ubf + (size_t)b*L_SEQ*PROJ + d;
  float* yb = ystate + (size_t)b*L_SEQ*PROJ + d;
  float s = 0.f;
  for (int l = base; l < L_SEQ; l += 8) {
    float4 d0 = *(const float4*)&dT[l];
    float4 d1 = *(const float4*)&dT[l+4];
    float4 f0 = *(const float4*)&sT[l];
    float4 f1 = *(const float4*)&sT[l+4];
    float dl[8] = {d0.x,d0.y,d0.z,d0.w,d1.x,d1.y,d1.z,d1.w};
    float sf[8] = {f0.x,f0.y,f0.z,f0.w,f1.x,f1.y,f1.z,f1.w};
    float uu[8], Bv[8], Cv[8];
#pragma unroll
    for (int t=0;t<8;t++){
      uu[t] = bf2f(ub[(size_t)(l+t)*PROJ]);
      const float* rp = P3b + (size_t)(l+t)*NCAT;
      Bv[t] = rp[0];
      Cv[t] = rp[32];
    }
#pragma unroll
    for (int t=0;t<8;t++){
      float decay = __expf(-dl[t]*np1);
      s = fmaf(decay, s, dl[t]*uu[t]*Bv[t]);
      float gte = 1.f/(1.f + 1e-12f*__expf(np1*sf[t]));  // overflow->inf->0, clean
      float contrib = s*gte*Cv[t];
#pragma unroll
      for (int m=16;m>0;m>>=1) contrib += __shfl_xor(contrib, m);
      if (n == 0) yb[(size_t)(l+t)*PROJ] = contrib;
    }
  }
}

// ---------------- z = (ystate_gated + u*D_skip) * x2 -> bf16 (l0-gated, no memset) ----------------
__global__ __launch_bounds__(256)
void zmul_kernel(const float* __restrict__ ystate, const unsigned short* __restrict__ ubf,
                 const unsigned short* __restrict__ x2bf, const float* __restrict__ Dskip,
                 const int* __restrict__ l0arr, unsigned short* __restrict__ zbf)
{
  size_t i = ((size_t)blockIdx.x*256 + threadIdx.x)*4;
  int d = (int)(i & (PROJ-1));
  int row = (int)(i >> 10);
  int l = row & (L_SEQ-1);
  int b = row >> 11;
  int4 l0v = *(const int4*)&l0arr[b*PROJ + d];
  float4 ys = *(const float4*)&ystate[i];
  ys.x = (l >= l0v.x) ? ys.x : 0.f;
  ys.y = (l >= l0v.y) ? ys.y : 0.f;
  ys.z = (l >= l0v.z) ? ys.z : 0.f;
  ys.w = (l >= l0v.w) ? ys.w : 0.f;
  ushort4 uu = *(const ushort4*)&ubf[i];
  ushort4 xx = *(const ushort4*)&x2bf[i];
  float4 Dv = *(const float4*)&Dskip[d];
  ushort4 o;
  o.x = f2bf((ys.x + bf2f(uu.x)*Dv.x)*bf2f(xx.x));
  o.y = f2bf((ys.y + bf2f(uu.y)*Dv.y)*bf2f(xx.y));
  o.z = f2bf((ys.z + bf2f(uu.z)*Dv.z)*bf2f(xx.z));
  o.w = f2bf((ys.w + bf2f(uu.w)*Dv.w)*bf2f(xx.w));
  *(ushort4*)&zbf[i] = o;
}

extern "C" void kernel_launch(void* const* d_in, const int* in_sizes, int n_in,
                              void* d_out, int out_size, void* d_ws, size_t ws_size,
                              hipStream_t stream)
{
  const float* x     = (const float*)d_in[0];
  const float* ln_g  = (const float*)d_in[1];
  const float* ln_b  = (const float*)d_in[2];
  const float* W1    = (const float*)d_in[3];
  const float* b1    = (const float*)d_in[4];
  const float* W2    = (const float*)d_in[5];
  const float* b2    = (const float*)d_in[6];
  const float* convk = (const float*)d_in[7];
  const float* convb = (const float*)d_in[8];
  const float* A_log = (const float*)d_in[9];
  const float* Dskip = (const float*)d_in[10];
  const float* WB    = (const float*)d_in[11];
  const float* bB    = (const float*)d_in[12];
  const float* WC    = (const float*)d_in[13];
  const float* bC    = (const float*)d_in[14];
  const float* Wd    = (const float*)d_in[15];
  const float* bd    = (const float*)d_in[16];
  const float* W3    = (const float*)d_in[17];
  const float* b3    = (const float*)d_in[18];

  char* w = (char*)d_ws;
  auto alloc = [&](size_t bytes){ char* p = w; w += (bytes + 255) & ~(size_t)255; return p; };
  unsigned short* Hbf    = (unsigned short*)alloc((size_t)ROWS*DMODEL*2);
  unsigned short* W12t   = (unsigned short*)alloc((size_t)2048*512*2);
  unsigned short* Wcatt  = (unsigned short*)alloc((size_t)NCAT*1024*2);
  unsigned short* W3t    = (unsigned short*)alloc((size_t)512*1024*2);
  float*          bias12 = (float*)alloc(2048*4);
  float*          biascat= (float*)alloc(NCAT*4);
  unsigned short* P12    = (unsigned short*)alloc((size_t)ROWS*2048*2);
  unsigned short* ubf    = (unsigned short*)alloc((size_t)ROWS*PROJ*2);
  unsigned short* x2bf   = (unsigned short*)alloc((size_t)ROWS*PROJ*2);
  float*          P3     = (float*)alloc((size_t)ROWS*NCAT*4);
  float*          deltaT = (float*)alloc((size_t)2048*L_SEQ*4);
  float*          sufshT = (float*)alloc((size_t)2048*L_SEQ*4);
  int*            l0arr  = (int*)alloc(2048*4);
  float*          ystate = (float*)alloc((size_t)ROWS*PROJ*4);
  unsigned short* zbf    = (unsigned short*)alloc((size_t)ROWS*PROJ*2);

  {
    int total = 2048*512 + NCAT*1024 + 512*1024 + 2048 + NCAT;
    prep_kernel<<<(total+255)/256, 256, 0, stream>>>(W1,b1,W2,b2,Wd,bd,WB,bB,WC,bC,W3,
                                                     W12t,Wcatt,W3t,bias12,biascat);
  }
  ln_kernel<<<ROWS/4, 256, 0, stream>>>(x, ln_g, ln_b, Hbf);

  dim3 g1(ROWS/128, 2048/64);
  gemm_bt<128,64,2,0><<<g1, 128, 0, stream>>>(Hbf, W12t, P12, bias12, nullptr, ROWS, 2048, DMODEL);

  conv_silu_kernel<<<ROWS*512/256, 256, 0, stream>>>(P12, convk, convb, ubf, x2bf);

  dim3 g2(ROWS/128, NCAT/64);
  gemm_bt<128,64,2,2><<<g2, 128, 0, stream>>>(ubf, Wcatt, P3, biascat, nullptr, ROWS, NCAT, PROJ);

  dim3 gt(L_SEQ/32, PROJ/32, BATCH);
  dtrans_kernel<<<gt, 256, 0, stream>>>(P3, deltaT);

  tsum_kernel<<<2048, 256, 0, stream>>>(deltaT, sufshT, l0arr);

  scan_kernel<<<2048/8, 256, 0, stream>>>(deltaT, sufshT, P3, ubf, A_log, l0arr, ystate);

  zmul_kernel<<<(ROWS*PROJ/4)/256, 256, 0, stream>>>(ystate, ubf, x2bf, Dskip, l0arr, zbf);

  dim3 g3(ROWS/64, DMODEL/64);
  gemm_bt<64,64,2,3><<<g3, 128, 0, stream>>>(zbf, W3t, (float*)d_out, b3, x, ROWS, DMODEL, PROJ);
}

// Round 7
// 162.559 us; speedup vs baseline: 1.1043x; 1.1043x over previous
//
#include <hip/hip_runtime.h>
#include <stdint.h>

#define L_SEQ 2048
#define BATCH 2
#define DMODEL 512
#define PROJ 1024
#define NST 32
#define NCAT 1152   // 1024 (Wd) + 32 (WB) + 32 (WC) + 64 pad
#define ROWS (BATCH*L_SEQ)  // 4096
#define THRESH 50.0f        // suffix cutoff (nats)

typedef float f32x4 __attribute__((ext_vector_type(4)));
typedef short short8 __attribute__((ext_vector_type(8)));

__device__ inline float bf2f(unsigned short u){ uint32_t x=((uint32_t)u)<<16; float f; __builtin_memcpy(&f,&x,4); return f; }
__device__ inline unsigned short f2bf(float f){ uint32_t x; __builtin_memcpy(&x,&f,4); uint32_t r=x+0x7FFFu+((x>>16)&1u); return (unsigned short)(r>>16); }
__device__ inline float siluf(float x){ return x/(1.f+__expf(-x)); }
__device__ inline float softplusf(float x){ return x>20.f? x : log1pf(__expf(x)); }

#define AS1(p) ((const __attribute__((address_space(1))) void*)(p))
#define AS3(p) ((__attribute__((address_space(3))) void*)(p))

template<int N> __device__ inline void wait_vmcnt(){
  if constexpr (N==0)      asm volatile("s_waitcnt vmcnt(0)" ::: "memory");
  else if constexpr (N==1) asm volatile("s_waitcnt vmcnt(1)" ::: "memory");
  else if constexpr (N==2) asm volatile("s_waitcnt vmcnt(2)" ::: "memory");
  else if constexpr (N==3) asm volatile("s_waitcnt vmcnt(3)" ::: "memory");
  else if constexpr (N==4) asm volatile("s_waitcnt vmcnt(4)" ::: "memory");
  else if constexpr (N==5) asm volatile("s_waitcnt vmcnt(5)" ::: "memory");
  else if constexpr (N==6) asm volatile("s_waitcnt vmcnt(6)" ::: "memory");
  else                     asm volatile("s_waitcnt vmcnt(8)" ::: "memory");
}

// ---------------- weight prep: fp32 -> bf16 transposed / concatenated ----------------
__global__ __launch_bounds__(256)
void prep_kernel(const float* __restrict__ W1, const float* __restrict__ b1,
                 const float* __restrict__ W2, const float* __restrict__ b2,
                 const float* __restrict__ Wd, const float* __restrict__ bd,
                 const float* __restrict__ WB, const float* __restrict__ bB,
                 const float* __restrict__ WC, const float* __restrict__ bC,
                 const float* __restrict__ W3,
                 unsigned short* __restrict__ W12t, unsigned short* __restrict__ Wcatt,
                 unsigned short* __restrict__ W3t, float* __restrict__ bias12,
                 float* __restrict__ biascat)
{
  int i = blockIdx.x*256 + threadIdx.x;
  const int nA = 2048*512;        // W12t [2048][512]
  const int nB = NCAT*1024;       // Wcatt [1152][1024]
  const int nC = 512*1024;        // W3t  [512][1024]
  if (i < nA) {
    int n = i >> 9, k = i & 511;
    float v = (n < 1024) ? W1[k*1024 + n] : W2[k*1024 + (n-1024)];
    W12t[i] = f2bf(v);
    return;
  }
  i -= nA;
  if (i < nB) {
    int n = i >> 10, k = i & 1023;
    float v;
    if (n < 1024) v = Wd[k*1024 + n];
    else if (n < 1056) v = WB[k*32 + (n-1024)];
    else if (n < 1088) v = WC[k*32 + (n-1056)];
    else v = 0.f;
    Wcatt[i] = f2bf(v);
    return;
  }
  i -= nB;
  if (i < nC) {
    int n = i >> 10, k = i & 1023;
    W3t[i] = f2bf(W3[k*512 + n]);
    return;
  }
  i -= nC;
  if (i < 2048) { bias12[i] = (i < 1024) ? b1[i] : b2[i-1024]; return; }
  i -= 2048;
  if (i < NCAT) {
    biascat[i] = (i < 1024) ? bd[i] : (i < 1056) ? bB[i-1024] : (i < 1088) ? bC[i-1056] : 0.f;
  }
}

// ---------------- LayerNorm: one wave per row of 512, write bf16 ----------------
__global__ __launch_bounds__(256)
void ln_kernel(const float* __restrict__ x, const float* __restrict__ gamma,
               const float* __restrict__ beta, unsigned short* __restrict__ H)
{
  int row = blockIdx.x*4 + (threadIdx.x >> 6);
  int lane = threadIdx.x & 63;
  const float4* xr = (const float4*)(x + (size_t)row*DMODEL);
  float4 v0 = xr[lane];
  float4 v1 = xr[lane+64];
  float s = v0.x+v0.y+v0.z+v0.w + v1.x+v1.y+v1.z+v1.w;
  float q = v0.x*v0.x+v0.y*v0.y+v0.z*v0.z+v0.w*v0.w
          + v1.x*v1.x+v1.y*v1.y+v1.z*v1.z+v1.w*v1.w;
#pragma unroll
  for (int m=32;m>0;m>>=1){ s += __shfl_xor(s,m); q += __shfl_xor(q,m); }
  float mu = s*(1.f/DMODEL);
  float var = q*(1.f/DMODEL) - mu*mu;
  float rs = rsqrtf(var + 1e-3f);
  int c0 = lane*4, c1 = 256 + lane*4;
  float4 g0 = *(const float4*)&gamma[c0]; float4 g1 = *(const float4*)&gamma[c1];
  float4 t0 = *(const float4*)&beta[c0];  float4 t1 = *(const float4*)&beta[c1];
  ushort4 o0, o1;
  o0.x = f2bf((v0.x-mu)*rs*g0.x + t0.x);
  o0.y = f2bf((v0.y-mu)*rs*g0.y + t0.y);
  o0.z = f2bf((v0.z-mu)*rs*g0.z + t0.z);
  o0.w = f2bf((v0.w-mu)*rs*g0.w + t0.w);
  o1.x = f2bf((v1.x-mu)*rs*g1.x + t1.x);
  o1.y = f2bf((v1.y-mu)*rs*g1.y + t1.y);
  o1.z = f2bf((v1.z-mu)*rs*g1.z + t1.z);
  o1.w = f2bf((v1.w-mu)*rs*g1.w + t1.w);
  *(ushort4*)&H[(size_t)row*DMODEL + c0] = o0;
  *(ushort4*)&H[(size_t)row*DMODEL + c1] = o1;
}

// ---------------- bf16 GEMM (r5 structure): 256 thr, 2x2 waves, depth-2, triple buf ----------------
// A[M,K] x Bt[N,K]^T -> C[M,N]. BK=32.
// MODE 0: +bias[col] -> bf16. MODE 2: +bias[col], softplus col<1024 -> fp32.
// MODE 3: +bias[col] +res -> fp32. MODE 4 (transposed): +bias[row], softplus row<1024 -> fp32.
template<int BM, int BN, int WR, int WC, int MODE>
__global__ __launch_bounds__(256)
void gemm_bt(const unsigned short* __restrict__ A, const unsigned short* __restrict__ Bt,
             void* __restrict__ Cv, const float* __restrict__ bias,
             const float* __restrict__ res, int M, int N, int K)
{
  constexpr int BMW = BM/WR, BNW = BN/WC;
  constexpr int AM = BMW/16, AN = BNW/16;
  constexpr int ASEGI = BM*4/256;
  constexpr int BSEGI = BN*4/256;
  constexpr int LPT = ASEGI + BSEGI;
  __shared__ unsigned short As[3][BM*32];
  __shared__ unsigned short Bs[3][BN*32];
  int tid = threadIdx.x;
  int lane = tid & 63, wid = tid >> 6;
  int wm = wid / WC, wn = wid % WC;
  int m0 = blockIdx.x*BM, n0 = blockIdx.y*BN;

  f32x4 acc[AM][AN];
#pragma unroll
  for (int i=0;i<AM;i++)
#pragma unroll
    for (int j=0;j<AN;j++)
#pragma unroll
      for (int e=0;e<4;e++) acc[i][j][e] = 0.f;

  // hoisted per-thread source pointers; LDS seg s=(row=s>>2, slot=s&3), k-chunk = slot^(row&3)
  const unsigned short* ap[ASEGI];
  const unsigned short* bp[BSEGI];
#pragma unroll
  for (int j=0;j<ASEGI;j++){
    int s = tid + j*256;
    int row = s >> 2, kc = ((s & 3) ^ (row & 3)) * 8;
    ap[j] = A + (size_t)(m0+row)*K + kc;
  }
#pragma unroll
  for (int j=0;j<BSEGI;j++){
    int s = tid + j*256;
    int row = s >> 2, kc = ((s & 3) ^ (row & 3)) * 8;
    bp[j] = Bt + (size_t)(n0+row)*K + kc;
  }

  auto stage = [&](int buf){
#pragma unroll
    for (int j=0;j<ASEGI;j++){
      __builtin_amdgcn_global_load_lds(AS1(ap[j]), AS3(&As[buf][(size_t)(j*256 + wid*64)*8]), 16, 0, 0);
      ap[j] += 32;
    }
#pragma unroll
    for (int j=0;j<BSEGI;j++){
      __builtin_amdgcn_global_load_lds(AS1(bp[j]), AS3(&Bs[buf][(size_t)(j*256 + wid*64)*8]), 16, 0, 0);
      bp[j] += 32;
    }
  };

  stage(0);
  stage(1);
  int T = K/32;
  int rb = 0, wb = 2;
  int r = lane & 15, kb = lane >> 4;
  int kbx = kb ^ (r & 3);                  // swizzled k-chunk slot
  for (int t = 0; t < T; ++t) {
    if (t+1 < T) wait_vmcnt<LPT>();        // stage(t) done; stage(t+1) in flight
    else         wait_vmcnt<0>();
    __builtin_amdgcn_s_barrier();
    if (t+2 < T) { stage(wb); wb = (wb==2)?0:wb+1; }
    short8 af[AM], bfr[AN];
#pragma unroll
    for (int i=0;i<AM;i++) af[i]  = *(const short8*)&As[rb][((wm*BMW + i*16 + r)*4 + kbx)*8];
#pragma unroll
    for (int j=0;j<AN;j++) bfr[j] = *(const short8*)&Bs[rb][((wn*BNW + j*16 + r)*4 + kbx)*8];
#pragma unroll
    for (int i=0;i<AM;i++)
#pragma unroll
      for (int j=0;j<AN;j++)
        acc[i][j] = __builtin_amdgcn_mfma_f32_16x16x32_bf16(af[i], bfr[j], acc[i][j], 0,0,0);
    rb = (rb==2)?0:rb+1;
  }

  int rr = (lane >> 4)*4, cc = lane & 15;
#pragma unroll
  for (int i=0;i<AM;i++)
#pragma unroll
    for (int j=0;j<AN;j++) {
      int col = n0 + wn*BNW + j*16 + cc;
      float bcol = (MODE == 4) ? 0.f : bias[col];
#pragma unroll
      for (int e=0;e<4;e++) {
        int row = m0 + wm*BMW + i*16 + rr + e;
        float v = acc[i][j][e];
        if constexpr (MODE == 4) {
          v += bias[row];
          if (row < 1024) v = softplusf(v);
          ((float*)Cv)[(size_t)row*N + col] = v;
        } else if constexpr (MODE == 0) {
          ((unsigned short*)Cv)[(size_t)row*N + col] = f2bf(v + bcol);
        } else if constexpr (MODE == 2) {
          v += bcol;
          if (col < 1024) v = softplusf(v);
          ((float*)Cv)[(size_t)row*N + col] = v;
        } else {
          v += bcol + res[(size_t)row*N + col];
          ((float*)Cv)[(size_t)row*N + col] = v;
        }
      }
    }
}

// ---------------- causal depthwise conv (K=4) + SiLU; also SiLU for x2 (bf16 in) ----------------
__global__ __launch_bounds__(256)
void conv_silu_kernel(const unsigned short* __restrict__ P12, const float* __restrict__ ck,
                      const float* __restrict__ cb, unsigned short* __restrict__ ubf,
                      unsigned short* __restrict__ x2bf)
{
  int gid = blockIdx.x*256 + threadIdx.x;   // ROWS * 512 tasks
  int c4 = gid & 511;
  int row = gid >> 9;
  int l = row & (L_SEQ-1);
  if (c4 < 256) {
    int c = c4*4;
    float4 bv = *(const float4*)&cb[c];
    float r0=bv.x, r1=bv.y, r2=bv.z, r3=bv.w;
#pragma unroll
    for (int t=0;t<4;t++){
      int lsrc = l - 3 + t;
      if (lsrc >= 0) {
        ushort4 xv = *(const ushort4*)&P12[(size_t)(row-3+t)*2048 + c];
        float4 kv = *(const float4*)&ck[t*PROJ + c];
        r0 = fmaf(bf2f(xv.x),kv.x,r0);
        r1 = fmaf(bf2f(xv.y),kv.y,r1);
        r2 = fmaf(bf2f(xv.z),kv.z,r2);
        r3 = fmaf(bf2f(xv.w),kv.w,r3);
      }
    }
    ushort4 o;
    o.x=f2bf(siluf(r0)); o.y=f2bf(siluf(r1)); o.z=f2bf(siluf(r2)); o.w=f2bf(siluf(r3));
    *(ushort4*)&ubf[(size_t)row*PROJ + c] = o;
  } else {
    int c = (c4-256)*4;
    ushort4 xv = *(const ushort4*)&P12[(size_t)row*2048 + 1024 + c];
    ushort4 o;
    o.x=f2bf(siluf(bf2f(xv.x))); o.y=f2bf(siluf(bf2f(xv.y)));
    o.z=f2bf(siluf(bf2f(xv.z))); o.w=f2bf(siluf(bf2f(xv.w)));
    *(ushort4*)&x2bf[(size_t)row*PROJ + c] = o;
  }
}

// ---------------- per-(b,d): 8-boundary suffix sums + l0, reading CT row d ----------------
__global__ __launch_bounds__(256)
void tsum_kernel(const float* __restrict__ CT, float* __restrict__ suf8,
                 int* __restrict__ l0out)
{
  int G = blockIdx.x;              // b*1024 + d
  int b = G >> 10, d = G & 1023;
  const float* row = CT + (size_t)d*ROWS + b*L_SEQ;
  int t = threadIdx.x;
  float4 v0 = *(const float4*)&row[t*8];
  float4 v1 = *(const float4*)&row[t*8+4];
  float vals[8] = {v0.x,v0.y,v0.z,v0.w,v1.x,v1.y,v1.z,v1.w};
  float part = 0.f;
#pragma unroll
  for (int i=0;i<8;i++) part += vals[i];
  __shared__ float ps[256];
  ps[t] = part; __syncthreads();
  for (int off=1; off<256; off<<=1){
    float v = (t >= off) ? ps[t-off] : 0.f;
    __syncthreads();
    ps[t] += v;
    __syncthreads();
  }
  float T = ps[255];
  float prefx = ps[t] - part;      // exclusive prefix of this thread's 8-chunk
  suf8[(size_t)G*(L_SEQ/8) + t] = T - prefx;   // suffix incl. position 8t
  float run = prefx; int cnt = 0;
#pragma unroll
  for (int i=0;i<8;i++){
    float suf_l = T - run;
    cnt += (suf_l >= THRESH) ? 1 : 0;
    run += vals[i];
  }
  __shared__ int cs[256];
  cs[t] = cnt; __syncthreads();
  for (int off=128; off>0; off>>=1){ if (t < off) cs[t] += cs[t+off]; __syncthreads(); }
  if (t == 0) {
    int total = cs[0];
    l0out[G] = total > 0 ? total-1 : 0;
  }
}

// ---------------- windowed gated selective scan: contiguous delta/B/C from CT ----------------
__global__ __launch_bounds__(256)
void scan_kernel(const float* __restrict__ CT, const float* __restrict__ suf8,
                 const unsigned short* __restrict__ ubf, const float* __restrict__ A_log,
                 const int* __restrict__ l0arr, float* __restrict__ ystate)
{
  int tid = threadIdx.x;
  int n = tid & 31;
  int G = blockIdx.x*8 + (tid >> 5);
  int b = G >> 10, d = G & 1023;
  float np1 = __expf(A_log[d*NST + n]);   // -A[d,n] = n+1
  int myl0 = l0arr[G];
  int base = min(myl0, __shfl_xor(myl0, 32)) & ~7;   // wave-uniform, 8-aligned
  const float* dT = CT + (size_t)d*ROWS + b*L_SEQ;           // softplus'd delta
  const float* Br = CT + (size_t)(1024+n)*ROWS + b*L_SEQ;
  const float* Cr = CT + (size_t)(1056+n)*ROWS + b*L_SEQ;
  const float* s8 = suf8 + (size_t)G*(L_SEQ/8);
  const unsigned short* ub = ubf + (size_t)b*L_SEQ*PROJ + d;
  float* yb = ystate + (size_t)b*L_SEQ*PROJ + d;
  float s = 0.f;
  for (int l = base; l < L_SEQ; l += 8) {
    float4 d0 = *(const float4*)&dT[l];
    float4 d1 = *(const float4*)&dT[l+4];
    float4 B0 = *(const float4*)&Br[l];
    float4 B1 = *(const float4*)&Br[l+4];
    float4 C0 = *(const float4*)&Cr[l];
    float4 C1 = *(const float4*)&Cr[l+4];
    float sufv = s8[l >> 3];                 // suffix incl. position l
    float dl[8] = {d0.x,d0.y,d0.z,d0.w,d1.x,d1.y,d1.z,d1.w};
    float Bv[8] = {B0.x,B0.y,B0.z,B0.w,B1.x,B1.y,B1.z,B1.w};
    float Cv[8] = {C0.x,C0.y,C0.z,C0.w,C1.x,C1.y,C1.z,C1.w};
    float uu[8];
#pragma unroll
    for (int t=0;t<8;t++) uu[t] = bf2f(ub[(size_t)(l+t)*PROJ]);
    float cum = 0.f;
#pragma unroll
    for (int t=0;t<8;t++){
      cum += dl[t];
      float decay = __expf(-dl[t]*np1);
      s = fmaf(decay, s, dl[t]*uu[t]*Bv[t]);
      float gte = 1.f/(1.f + 1e-12f*__expf(np1*(sufv - cum)));  // overflow->inf->0
      float contrib = s*gte*Cv[t];
#pragma unroll
      for (int m=16;m>0;m>>=1) contrib += __shfl_xor(contrib, m);
      if (n == 0) yb[(size_t)(l+t)*PROJ] = contrib;
    }
  }
}

// ---------------- z = (ystate_gated + u*D_skip) * x2 -> bf16 (l0-gated, no memset) ----------------
__global__ __launch_bounds__(256)
void zmul_kernel(const float* __restrict__ ystate, const unsigned short* __restrict__ ubf,
                 const unsigned short* __restrict__ x2bf, const float* __restrict__ Dskip,
                 const int* __restrict__ l0arr, unsigned short* __restrict__ zbf)
{
  size_t i = ((size_t)blockIdx.x*256 + threadIdx.x)*4;
  int d = (int)(i & (PROJ-1));
  int row = (int)(i >> 10);
  int l = row & (L_SEQ-1);
  int b = row >> 11;
  int4 l0v = *(const int4*)&l0arr[b*PROJ + d];
  float4 ys = *(const float4*)&ystate[i];
  ys.x = (l >= l0v.x) ? ys.x : 0.f;
  ys.y = (l >= l0v.y) ? ys.y : 0.f;
  ys.z = (l >= l0v.z) ? ys.z : 0.f;
  ys.w = (l >= l0v.w) ? ys.w : 0.f;
  ushort4 uu = *(const ushort4*)&ubf[i];
  ushort4 xx = *(const ushort4*)&x2bf[i];
  float4 Dv = *(const float4*)&Dskip[d];
  ushort4 o;
  o.x = f2bf((ys.x + bf2f(uu.x)*Dv.x)*bf2f(xx.x));
  o.y = f2bf((ys.y + bf2f(uu.y)*Dv.y)*bf2f(xx.y));
  o.z = f2bf((ys.z + bf2f(uu.z)*Dv.z)*bf2f(xx.z));
  o.w = f2bf((ys.w + bf2f(uu.w)*Dv.w)*bf2f(xx.w));
  *(ushort4*)&zbf[i] = o;
}

extern "C" void kernel_launch(void* const* d_in, const int* in_sizes, int n_in,
                              void* d_out, int out_size, void* d_ws, size_t ws_size,
                              hipStream_t stream)
{
  const float* x     = (const float*)d_in[0];
  const float* ln_g  = (const float*)d_in[1];
  const float* ln_b  = (const float*)d_in[2];
  const float* W1    = (const float*)d_in[3];
  const float* b1    = (const float*)d_in[4];
  const float* W2    = (const float*)d_in[5];
  const float* b2    = (const float*)d_in[6];
  const float* convk = (const float*)d_in[7];
  const float* convb = (const float*)d_in[8];
  const float* A_log = (const float*)d_in[9];
  const float* Dskip = (const float*)d_in[10];
  const float* WB    = (const float*)d_in[11];
  const float* bB    = (const float*)d_in[12];
  const float* WC    = (const float*)d_in[13];
  const float* bC    = (const float*)d_in[14];
  const float* Wd    = (const float*)d_in[15];
  const float* bd    = (const float*)d_in[16];
  const float* W3    = (const float*)d_in[17];
  const float* b3    = (const float*)d_in[18];

  char* w = (char*)d_ws;
  auto alloc = [&](size_t bytes){ char* p = w; w += (bytes + 255) & ~(size_t)255; return p; };
  unsigned short* Hbf    = (unsigned short*)alloc((size_t)ROWS*DMODEL*2);
  unsigned short* W12t   = (unsigned short*)alloc((size_t)2048*512*2);
  unsigned short* Wcatt  = (unsigned short*)alloc((size_t)NCAT*1024*2);
  unsigned short* W3t    = (unsigned short*)alloc((size_t)512*1024*2);
  float*          bias12 = (float*)alloc(2048*4);
  float*          biascat= (float*)alloc(NCAT*4);
  unsigned short* P12    = (unsigned short*)alloc((size_t)ROWS*2048*2);
  unsigned short* ubf    = (unsigned short*)alloc((size_t)ROWS*PROJ*2);
  unsigned short* x2bf   = (unsigned short*)alloc((size_t)ROWS*PROJ*2);
  float*          CT     = (float*)alloc((size_t)NCAT*ROWS*4);   // transposed gemm2 out
  float*          suf8   = (float*)alloc((size_t)2048*(L_SEQ/8)*4);
  int*            l0arr  = (int*)alloc(2048*4);
  float*          ystate = (float*)alloc((size_t)ROWS*PROJ*4);
  unsigned short* zbf    = (unsigned short*)alloc((size_t)ROWS*PROJ*2);

  {
    int total = 2048*512 + NCAT*1024 + 512*1024 + 2048 + NCAT;
    prep_kernel<<<(total+255)/256, 256, 0, stream>>>(W1,b1,W2,b2,Wd,bd,WB,bB,WC,bC,W3,
                                                     W12t,Wcatt,W3t,bias12,biascat);
  }
  ln_kernel<<<ROWS/4, 256, 0, stream>>>(x, ln_g, ln_b, Hbf);

  dim3 g1(ROWS/64, 2048/64);
  gemm_bt<64,64,2,2,0><<<g1, 256, 0, stream>>>(Hbf, W12t, P12, bias12, nullptr, ROWS, 2048, DMODEL);

  conv_silu_kernel<<<ROWS*512/256, 256, 0, stream>>>(P12, convk, convb, ubf, x2bf);

  // transposed: CT[NCAT][ROWS] = Wcatt x ubf^T
  dim3 g2(NCAT/64, ROWS/64);
  gemm_bt<64,64,2,2,4><<<g2, 256, 0, stream>>>(Wcatt, ubf, CT, biascat, nullptr, NCAT, ROWS, PROJ);

  tsum_kernel<<<2048, 256, 0, stream>>>(CT, suf8, l0arr);

  scan_kernel<<<2048/8, 256, 0, stream>>>(CT, suf8, ubf, A_log, l0arr, ystate);

  zmul_kernel<<<(ROWS*PROJ/4)/256, 256, 0, stream>>>(ystate, ubf, x2bf, Dskip, l0arr, zbf);

  dim3 g3(ROWS/64, DMODEL/64);
  gemm_bt<64,64,2,2,3><<<g3, 256, 0, stream>>>(zbf, W3t, (float*)d_out, b3, x, ROWS, DMODEL, PROJ);
}

// Round 8
// 160.184 us; speedup vs baseline: 1.1206x; 1.0148x over previous
//
#include <hip/hip_runtime.h>
#include <stdint.h>

#define L_SEQ 2048
#define BATCH 2
#define DMODEL 512
#define PROJ 1024
#define NST 32
#define NCATU 1088  // 1024 (Wd) + 32 (WB) + 32 (WC) -> 17*64
#define ROWS (BATCH*L_SEQ)  // 4096
#define THRESH 50.0f        // suffix cutoff (nats)

typedef float f32x4 __attribute__((ext_vector_type(4)));
typedef short short8 __attribute__((ext_vector_type(8)));

__device__ inline float bf2f(unsigned short u){ uint32_t x=((uint32_t)u)<<16; float f; __builtin_memcpy(&f,&x,4); return f; }
__device__ inline unsigned short f2bf(float f){ uint32_t x; __builtin_memcpy(&x,&f,4); uint32_t r=x+0x7FFFu+((x>>16)&1u); return (unsigned short)(r>>16); }
__device__ inline float siluf(float x){ return x/(1.f+__expf(-x)); }
__device__ inline float softplusf(float x){ return x>20.f? x : log1pf(__expf(x)); }

#define AS1(p) ((const __attribute__((address_space(1))) void*)(p))
#define AS3(p) ((__attribute__((address_space(3))) void*)(p))

template<int N> __device__ inline void wait_vmcnt(){
  if constexpr (N==0)      asm volatile("s_waitcnt vmcnt(0)" ::: "memory");
  else if constexpr (N==2) asm volatile("s_waitcnt vmcnt(2)" ::: "memory");
  else if constexpr (N==4) asm volatile("s_waitcnt vmcnt(4)" ::: "memory");
  else if constexpr (N==6) asm volatile("s_waitcnt vmcnt(6)" ::: "memory");
  else                     asm volatile("s_waitcnt vmcnt(8)" ::: "memory");
}

// ---------------- weight prep: fp32 -> bf16 transposed / concatenated ----------------
__global__ __launch_bounds__(256)
void prep_kernel(const float* __restrict__ W1, const float* __restrict__ b1,
                 const float* __restrict__ W2, const float* __restrict__ b2,
                 const float* __restrict__ Wd, const float* __restrict__ bd,
                 const float* __restrict__ WB, const float* __restrict__ bB,
                 const float* __restrict__ WC, const float* __restrict__ bC,
                 const float* __restrict__ W3,
                 unsigned short* __restrict__ W12t, unsigned short* __restrict__ Wcatt,
                 unsigned short* __restrict__ W3t, float* __restrict__ bias12,
                 float* __restrict__ biascat)
{
  int i = blockIdx.x*256 + threadIdx.x;
  const int nA = 2048*512;        // W12t [2048][512]
  const int nB = NCATU*1024;      // Wcatt [1088][1024]
  const int nC = 512*1024;        // W3t  [512][1024]
  if (i < nA) {
    int n = i >> 9, k = i & 511;
    float v = (n < 1024) ? W1[k*1024 + n] : W2[k*1024 + (n-1024)];
    W12t[i] = f2bf(v);
    return;
  }
  i -= nA;
  if (i < nB) {
    int n = i >> 10, k = i & 1023;
    float v;
    if (n < 1024) v = Wd[k*1024 + n];
    else if (n < 1056) v = WB[k*32 + (n-1024)];
    else v = WC[k*32 + (n-1056)];
    Wcatt[i] = f2bf(v);
    return;
  }
  i -= nB;
  if (i < nC) {
    int n = i >> 10, k = i & 1023;
    W3t[i] = f2bf(W3[k*512 + n]);
    return;
  }
  i -= nC;
  if (i < 2048) { bias12[i] = (i < 1024) ? b1[i] : b2[i-1024]; return; }
  i -= 2048;
  if (i < NCATU) {
    biascat[i] = (i < 1024) ? bd[i] : (i < 1056) ? bB[i-1024] : bC[i-1056];
  }
}

// ---------------- LayerNorm: one wave per row of 512, write bf16 ----------------
__global__ __launch_bounds__(256)
void ln_kernel(const float* __restrict__ x, const float* __restrict__ gamma,
               const float* __restrict__ beta, unsigned short* __restrict__ H)
{
  int row = blockIdx.x*4 + (threadIdx.x >> 6);
  int lane = threadIdx.x & 63;
  const float4* xr = (const float4*)(x + (size_t)row*DMODEL);
  float4 v0 = xr[lane];
  float4 v1 = xr[lane+64];
  float s = v0.x+v0.y+v0.z+v0.w + v1.x+v1.y+v1.z+v1.w;
  float q = v0.x*v0.x+v0.y*v0.y+v0.z*v0.z+v0.w*v0.w
          + v1.x*v1.x+v1.y*v1.y+v1.z*v1.z+v1.w*v1.w;
#pragma unroll
  for (int m=32;m>0;m>>=1){ s += __shfl_xor(s,m); q += __shfl_xor(q,m); }
  float mu = s*(1.f/DMODEL);
  float var = q*(1.f/DMODEL) - mu*mu;
  float rs = rsqrtf(var + 1e-3f);
  int c0 = lane*4, c1 = 256 + lane*4;
  float4 g0 = *(const float4*)&gamma[c0]; float4 g1 = *(const float4*)&gamma[c1];
  float4 t0 = *(const float4*)&beta[c0];  float4 t1 = *(const float4*)&beta[c1];
  ushort4 o0, o1;
  o0.x = f2bf((v0.x-mu)*rs*g0.x + t0.x);
  o0.y = f2bf((v0.y-mu)*rs*g0.y + t0.y);
  o0.z = f2bf((v0.z-mu)*rs*g0.z + t0.z);
  o0.w = f2bf((v0.w-mu)*rs*g0.w + t0.w);
  o1.x = f2bf((v1.x-mu)*rs*g1.x + t1.x);
  o1.y = f2bf((v1.y-mu)*rs*g1.y + t1.y);
  o1.z = f2bf((v1.z-mu)*rs*g1.z + t1.z);
  o1.w = f2bf((v1.w-mu)*rs*g1.w + t1.w);
  *(ushort4*)&H[(size_t)row*DMODEL + c0] = o0;
  *(ushort4*)&H[(size_t)row*DMODEL + c1] = o1;
}

// ---------------- bf16 GEMM: BK=64, depth-2 prefetch, triple-buffer, counted vmcnt ----------------
// A[M,K] x Bt[N,K]^T -> C[M,N]. 256 threads, 2x2 waves, each wave 32x32 out.
// XCD-chunked block swizzle (requires gridDim.x*gridDim.y % 8 == 0).
// MODE 0: +bias[col] -> bf16. MODE 3: +bias[col]+res -> fp32.
// MODE 4 (transposed): +bias[row], softplus row<1024 -> fp32.
template<int BM, int BN, int MODE>
__global__ __launch_bounds__(256)
void gemm_bt(const unsigned short* __restrict__ A, const unsigned short* __restrict__ Bt,
             void* __restrict__ Cv, const float* __restrict__ bias,
             const float* __restrict__ res, int M, int N, int K)
{
  constexpr int BK = 64;
  constexpr int AM = 2, AN = 2;                  // per-wave 32x32 out
  constexpr int ASEGI = BM*BK/8/256;             // =2 gload_lds per thread per matrix
  constexpr int BSEGI = BN*BK/8/256;
  constexpr int LPT = ASEGI + BSEGI;             // =4
  __shared__ unsigned short As[3][BM*BK];
  __shared__ unsigned short Bs[3][BN*BK];
  int tid = threadIdx.x;
  int lane = tid & 63, wid = tid >> 6;
  int wm = wid >> 1, wn = wid & 1;

  // XCD-chunked bijective swizzle on linear block id
  int gx = gridDim.x;
  int nwg = gx * gridDim.y;
  int L = blockIdx.y*gx + blockIdx.x;
  int W = (L & 7)*(nwg >> 3) + (L >> 3);
  int bx = W % gx, by = W / gx;
  int m0 = bx*BM, n0 = by*BN;

  f32x4 acc[AM][AN];
#pragma unroll
  for (int i=0;i<AM;i++)
#pragma unroll
    for (int j=0;j<AN;j++)
#pragma unroll
      for (int e=0;e<4;e++) acc[i][j][e] = 0.f;

  // hoisted per-thread source pointers; LDS seg s=(row=s>>3, slot=s&7),
  // slot holds source k-chunk = slot^(row&7)  [XOR swizzle on source]
  const unsigned short* ap[ASEGI];
  const unsigned short* bp[BSEGI];
#pragma unroll
  for (int j=0;j<ASEGI;j++){
    int s = tid + j*256;
    int row = s >> 3, kc = ((s & 7) ^ (row & 7)) * 8;
    ap[j] = A + (size_t)(m0+row)*K + kc;
  }
#pragma unroll
  for (int j=0;j<BSEGI;j++){
    int s = tid + j*256;
    int row = s >> 3, kc = ((s & 7) ^ (row & 7)) * 8;
    bp[j] = Bt + (size_t)(n0+row)*K + kc;
  }

  auto stage = [&](int buf){
#pragma unroll
    for (int j=0;j<ASEGI;j++){
      __builtin_amdgcn_global_load_lds(AS1(ap[j]), AS3(&As[buf][(size_t)(j*256 + wid*64)*8]), 16, 0, 0);
      ap[j] += BK;
    }
#pragma unroll
    for (int j=0;j<BSEGI;j++){
      __builtin_amdgcn_global_load_lds(AS1(bp[j]), AS3(&Bs[buf][(size_t)(j*256 + wid*64)*8]), 16, 0, 0);
      bp[j] += BK;
    }
  };

  stage(0);
  stage(1);
  int T = K/BK;
  int rb = 0, wb = 2;
  int r = lane & 15, kb = lane >> 4;   // kb 0..3 -> 8-elem chunk within 32-slice
  for (int t = 0; t < T; ++t) {
    if (t+1 < T) wait_vmcnt<LPT>();    // stage(t) done; stage(t+1) in flight
    else         wait_vmcnt<0>();
    __builtin_amdgcn_s_barrier();
    if (t+2 < T) { stage(wb); wb = (wb==2)?0:wb+1; }
#pragma unroll
    for (int ks=0; ks<2; ++ks) {
      short8 af[AM], bfr[AN];
#pragma unroll
      for (int i=0;i<AM;i++){
        int row = wm*32 + i*16 + r;
        int c = (ks*4 + kb) ^ (r & 7);
        af[i] = *(const short8*)&As[rb][(row*8 + c)*8];
      }
#pragma unroll
      for (int j=0;j<AN;j++){
        int row = wn*32 + j*16 + r;
        int c = (ks*4 + kb) ^ (r & 7);
        bfr[j] = *(const short8*)&Bs[rb][(row*8 + c)*8];
      }
#pragma unroll
      for (int i=0;i<AM;i++)
#pragma unroll
        for (int j=0;j<AN;j++)
          acc[i][j] = __builtin_amdgcn_mfma_f32_16x16x32_bf16(af[i], bfr[j], acc[i][j], 0,0,0);
    }
    rb = (rb==2)?0:rb+1;
  }

  int rr = (lane >> 4)*4, cc = lane & 15;
#pragma unroll
  for (int i=0;i<AM;i++)
#pragma unroll
    for (int j=0;j<AN;j++) {
      int col = n0 + wn*32 + j*16 + cc;
      float bcol = (MODE == 4) ? 0.f : bias[col];
#pragma unroll
      for (int e=0;e<4;e++) {
        int row = m0 + wm*32 + i*16 + rr + e;
        float v = acc[i][j][e];
        if constexpr (MODE == 4) {
          v += bias[row];
          if (row < 1024) v = softplusf(v);
          ((float*)Cv)[(size_t)row*N + col] = v;
        } else if constexpr (MODE == 0) {
          ((unsigned short*)Cv)[(size_t)row*N + col] = f2bf(v + bcol);
        } else {
          v += bcol + res[(size_t)row*N + col];
          ((float*)Cv)[(size_t)row*N + col] = v;
        }
      }
    }
}

// ---------------- causal depthwise conv (K=4) + SiLU; also SiLU for x2 (bf16 in) ----------------
__global__ __launch_bounds__(256)
void conv_silu_kernel(const unsigned short* __restrict__ P12, const float* __restrict__ ck,
                      const float* __restrict__ cb, unsigned short* __restrict__ ubf,
                      unsigned short* __restrict__ x2bf)
{
  int gid = blockIdx.x*256 + threadIdx.x;   // ROWS * 512 tasks
  int c4 = gid & 511;
  int row = gid >> 9;
  int l = row & (L_SEQ-1);
  if (c4 < 256) {
    int c = c4*4;
    float4 bv = *(const float4*)&cb[c];
    float r0=bv.x, r1=bv.y, r2=bv.z, r3=bv.w;
#pragma unroll
    for (int t=0;t<4;t++){
      int lsrc = l - 3 + t;
      if (lsrc >= 0) {
        ushort4 xv = *(const ushort4*)&P12[(size_t)(row-3+t)*2048 + c];
        float4 kv = *(const float4*)&ck[t*PROJ + c];
        r0 = fmaf(bf2f(xv.x),kv.x,r0);
        r1 = fmaf(bf2f(xv.y),kv.y,r1);
        r2 = fmaf(bf2f(xv.z),kv.z,r2);
        r3 = fmaf(bf2f(xv.w),kv.w,r3);
      }
    }
    ushort4 o;
    o.x=f2bf(siluf(r0)); o.y=f2bf(siluf(r1)); o.z=f2bf(siluf(r2)); o.w=f2bf(siluf(r3));
    *(ushort4*)&ubf[(size_t)row*PROJ + c] = o;
  } else {
    int c = (c4-256)*4;
    ushort4 xv = *(const ushort4*)&P12[(size_t)row*2048 + 1024 + c];
    ushort4 o;
    o.x=f2bf(siluf(bf2f(xv.x))); o.y=f2bf(siluf(bf2f(xv.y)));
    o.z=f2bf(siluf(bf2f(xv.z))); o.w=f2bf(siluf(bf2f(xv.w)));
    *(ushort4*)&x2bf[(size_t)row*PROJ + c] = o;
  }
}

// ---------------- per-(b,d): 8-boundary suffix sums + l0, reading CT row d ----------------
__global__ __launch_bounds__(256)
void tsum_kernel(const float* __restrict__ CT, float* __restrict__ suf8,
                 int* __restrict__ l0out)
{
  int G = blockIdx.x;              // b*1024 + d
  int b = G >> 10, d = G & 1023;
  const float* row = CT + (size_t)d*ROWS + b*L_SEQ;
  int t = threadIdx.x;
  float4 v0 = *(const float4*)&row[t*8];
  float4 v1 = *(const float4*)&row[t*8+4];
  float vals[8] = {v0.x,v0.y,v0.z,v0.w,v1.x,v1.y,v1.z,v1.w};
  float part = 0.f;
#pragma unroll
  for (int i=0;i<8;i++) part += vals[i];
  __shared__ float ps[256];
  ps[t] = part; __syncthreads();
  for (int off=1; off<256; off<<=1){
    float v = (t >= off) ? ps[t-off] : 0.f;
    __syncthreads();
    ps[t] += v;
    __syncthreads();
  }
  float T = ps[255];
  float prefx = ps[t] - part;      // exclusive prefix of this thread's 8-chunk
  suf8[(size_t)G*(L_SEQ/8) + t] = T - prefx;   // suffix incl. position 8t
  float run = prefx; int cnt = 0;
#pragma unroll
  for (int i=0;i<8;i++){
    float suf_l = T - run;
    cnt += (suf_l >= THRESH) ? 1 : 0;
    run += vals[i];
  }
  __shared__ int cs[256];
  cs[t] = cnt; __syncthreads();
  for (int off=128; off>0; off>>=1){ if (t < off) cs[t] += cs[t+off]; __syncthreads(); }
  if (t == 0) {
    int total = cs[0];
    l0out[G] = total > 0 ? total-1 : 0;
  }
}

// ---------------- windowed gated selective scan: contiguous delta/B/C from CT ----------------
__global__ __launch_bounds__(256)
void scan_kernel(const float* __restrict__ CT, const float* __restrict__ suf8,
                 const unsigned short* __restrict__ ubf, const float* __restrict__ A_log,
                 const int* __restrict__ l0arr, float* __restrict__ ystate)
{
  int tid = threadIdx.x;
  int n = tid & 31;
  int G = blockIdx.x*8 + (tid >> 5);
  int b = G >> 10, d = G & 1023;
  float np1 = __expf(A_log[d*NST + n]);   // -A[d,n] = n+1
  int myl0 = l0arr[G];
  int base = min(myl0, __shfl_xor(myl0, 32)) & ~7;   // wave-uniform, 8-aligned
  const float* dT = CT + (size_t)d*ROWS + b*L_SEQ;           // softplus'd delta
  const float* Br = CT + (size_t)(1024+n)*ROWS + b*L_SEQ;
  const float* Cr = CT + (size_t)(1056+n)*ROWS + b*L_SEQ;
  const float* s8 = suf8 + (size_t)G*(L_SEQ/8);
  const unsigned short* ub = ubf + (size_t)b*L_SEQ*PROJ + d;
  float* yb = ystate + (size_t)b*L_SEQ*PROJ + d;
  float s = 0.f;
  for (int l = base; l < L_SEQ; l += 8) {
    float4 d0 = *(const float4*)&dT[l];
    float4 d1 = *(const float4*)&dT[l+4];
    float4 B0 = *(const float4*)&Br[l];
    float4 B1 = *(const float4*)&Br[l+4];
    float4 C0 = *(const float4*)&Cr[l];
    float4 C1 = *(const float4*)&Cr[l+4];
    float sufv = s8[l >> 3];                 // suffix incl. position l
    float dl[8] = {d0.x,d0.y,d0.z,d0.w,d1.x,d1.y,d1.z,d1.w};
    float Bv[8] = {B0.x,B0.y,B0.z,B0.w,B1.x,B1.y,B1.z,B1.w};
    float Cv[8] = {C0.x,C0.y,C0.z,C0.w,C1.x,C1.y,C1.z,C1.w};
    float uu[8];
#pragma unroll
    for (int t=0;t<8;t++) uu[t] = bf2f(ub[(size_t)(l+t)*PROJ]);
    float cum = 0.f;
#pragma unroll
    for (int t=0;t<8;t++){
      cum += dl[t];
      float decay = __expf(-dl[t]*np1);
      s = fmaf(decay, s, dl[t]*uu[t]*Bv[t]);
      float gte = 1.f/(1.f + 1e-12f*__expf(np1*(sufv - cum)));  // overflow->inf->0
      float contrib = s*gte*Cv[t];
#pragma unroll
      for (int m=16;m>0;m>>=1) contrib += __shfl_xor(contrib, m);
      if (n == 0) yb[(size_t)(l+t)*PROJ] = contrib;
    }
  }
}

// ---------------- z = (ystate_gated + u*D_skip) * x2 -> bf16 (l0-gated, no memset) ----------------
__global__ __launch_bounds__(256)
void zmul_kernel(const float* __restrict__ ystate, const unsigned short* __restrict__ ubf,
                 const unsigned short* __restrict__ x2bf, const float* __restrict__ Dskip,
                 const int* __restrict__ l0arr, unsigned short* __restrict__ zbf)
{
  size_t i = ((size_t)blockIdx.x*256 + threadIdx.x)*4;
  int d = (int)(i & (PROJ-1));
  int row = (int)(i >> 10);
  int l = row & (L_SEQ-1);
  int b = row >> 11;
  int4 l0v = *(const int4*)&l0arr[b*PROJ + d];
  float4 ys = *(const float4*)&ystate[i];
  ys.x = (l >= l0v.x) ? ys.x : 0.f;
  ys.y = (l >= l0v.y) ? ys.y : 0.f;
  ys.z = (l >= l0v.z) ? ys.z : 0.f;
  ys.w = (l >= l0v.w) ? ys.w : 0.f;
  ushort4 uu = *(const ushort4*)&ubf[i];
  ushort4 xx = *(const ushort4*)&x2bf[i];
  float4 Dv = *(const float4*)&Dskip[d];
  ushort4 o;
  o.x = f2bf((ys.x + bf2f(uu.x)*Dv.x)*bf2f(xx.x));
  o.y = f2bf((ys.y + bf2f(uu.y)*Dv.y)*bf2f(xx.y));
  o.z = f2bf((ys.z + bf2f(uu.z)*Dv.z)*bf2f(xx.z));
  o.w = f2bf((ys.w + bf2f(uu.w)*Dv.w)*bf2f(xx.w));
  *(ushort4*)&zbf[i] = o;
}

extern "C" void kernel_launch(void* const* d_in, const int* in_sizes, int n_in,
                              void* d_out, int out_size, void* d_ws, size_t ws_size,
                              hipStream_t stream)
{
  const float* x     = (const float*)d_in[0];
  const float* ln_g  = (const float*)d_in[1];
  const float* ln_b  = (const float*)d_in[2];
  const float* W1    = (const float*)d_in[3];
  const float* b1    = (const float*)d_in[4];
  const float* W2    = (const float*)d_in[5];
  const float* b2    = (const float*)d_in[6];
  const float* convk = (const float*)d_in[7];
  const float* convb = (const float*)d_in[8];
  const float* A_log = (const float*)d_in[9];
  const float* Dskip = (const float*)d_in[10];
  const float* WB    = (const float*)d_in[11];
  const float* bB    = (const float*)d_in[12];
  const float* WC    = (const float*)d_in[13];
  const float* bC    = (const float*)d_in[14];
  const float* Wd    = (const float*)d_in[15];
  const float* bd    = (const float*)d_in[16];
  const float* W3    = (const float*)d_in[17];
  const float* b3    = (const float*)d_in[18];

  char* w = (char*)d_ws;
  auto alloc = [&](size_t bytes){ char* p = w; w += (bytes + 255) & ~(size_t)255; return p; };
  unsigned short* Hbf    = (unsigned short*)alloc((size_t)ROWS*DMODEL*2);
  unsigned short* W12t   = (unsigned short*)alloc((size_t)2048*512*2);
  unsigned short* Wcatt  = (unsigned short*)alloc((size_t)NCATU*1024*2);
  unsigned short* W3t    = (unsigned short*)alloc((size_t)512*1024*2);
  float*          bias12 = (float*)alloc(2048*4);
  float*          biascat= (float*)alloc(NCATU*4);
  unsigned short* P12    = (unsigned short*)alloc((size_t)ROWS*2048*2);
  unsigned short* ubf    = (unsigned short*)alloc((size_t)ROWS*PROJ*2);
  unsigned short* x2bf   = (unsigned short*)alloc((size_t)ROWS*PROJ*2);
  float*          CT     = (float*)alloc((size_t)NCATU*ROWS*4);   // transposed gemm2 out
  float*          suf8   = (float*)alloc((size_t)2048*(L_SEQ/8)*4);
  int*            l0arr  = (int*)alloc(2048*4);
  float*          ystate = (float*)alloc((size_t)ROWS*PROJ*4);
  unsigned short* zbf    = (unsigned short*)alloc((size_t)ROWS*PROJ*2);

  {
    int total = 2048*512 + NCATU*1024 + 512*1024 + 2048 + NCATU;
    prep_kernel<<<(total+255)/256, 256, 0, stream>>>(W1,b1,W2,b2,Wd,bd,WB,bB,WC,bC,W3,
                                                     W12t,Wcatt,W3t,bias12,biascat);
  }
  ln_kernel<<<ROWS/4, 256, 0, stream>>>(x, ln_g, ln_b, Hbf);

  dim3 g1(ROWS/64, 2048/64);   // 2048 blocks
  gemm_bt<64,64,0><<<g1, 256, 0, stream>>>(Hbf, W12t, P12, bias12, nullptr, ROWS, 2048, DMODEL);

  conv_silu_kernel<<<ROWS*512/256, 256, 0, stream>>>(P12, convk, convb, ubf, x2bf);

  // transposed: CT[NCATU][ROWS] = Wcatt x ubf^T
  dim3 g2(NCATU/64, ROWS/64);  // 17 x 64 = 1088 blocks
  gemm_bt<64,64,4><<<g2, 256, 0, stream>>>(Wcatt, ubf, CT, biascat, nullptr, NCATU, ROWS, PROJ);

  tsum_kernel<<<2048, 256, 0, stream>>>(CT, suf8, l0arr);

  scan_kernel<<<2048/8, 256, 0, stream>>>(CT, suf8, ubf, A_log, l0arr, ystate);

  zmul_kernel<<<(ROWS*PROJ/4)/256, 256, 0, stream>>>(ystate, ubf, x2bf, Dskip, l0arr, zbf);

  dim3 g3(ROWS/64, DMODEL/64); // 512 blocks
  gemm_bt<64,64,3><<<g3, 256, 0, stream>>>(zbf, W3t, (float*)d_out, b3, x, ROWS, DMODEL, PROJ);
}